// Round 2
// baseline (758.422 us; speedup 1.0000x reference)
//
#include <hip/hip_runtime.h>
#include <hip/hip_bf16.h>

typedef __hip_bfloat16 bf16;
typedef __attribute__((ext_vector_type(8))) short bshort8;
typedef __attribute__((ext_vector_type(4))) float float4v;
typedef __attribute__((ext_vector_type(4))) unsigned short ushort4v;

#define N_NODES 10000
#define N_EDGES 320000
#define IN_DIM  128
#define HID_DIM 256
#define OUT_DIM 128

// ---- d_out layout (fp32 elements) ----
// out_x : floats [0          , 1,280,000)    bytes [0          , 5,120,000)
// out_s : floats [1,280,000  , 101,280,000)  bytes [5,120,000  , 405,120,000)
// out_h : floats [101,280,000, 102,560,000)  bytes [405,120,000, 410,240,000)
//
// Scratch lives inside the out_s byte-region (dead before k_sgemm writes it);
// hs (bf16 staging of h_) lives in the out_h region (overwritten by the final
// h-passthrough memcpy AFTER k_sgemm has consumed it). d_ws deliberately unused.
#define SC_BUF1 5120000ull     // hid   [10000,256] f32 = 10,240,000 B
#define SC_BUF2 15360000ull    // xw2   [10000,128] f32 =  5,120,000 B
#define SC_AGGX 20480000ull    // A*x   [10000,128] f32 =  5,120,000 B (shared by branches)
#define SC_ESRC 25600000ull    // 320000 i32 = 1,280,000 B
#define SC_CNT  26880000ull    // 10000 i32
#define SC_CUR  26920192ull    // 10000 i32
#define SC_RPTR 26960384ull    // 10001 i32
#define SC_DINV 27000576ull    // 10000 f32 (ends 27,040,576 << 405,120,000)
#define OFF_HS  405120000ull   // 10000x128 bf16 = 2,560,000 B (inside out_h's 5.12 MB)

__global__ void k_zero(int* __restrict__ cnt, int* __restrict__ cur) {
    int i = blockIdx.x * blockDim.x + threadIdx.x;
    if (i < N_NODES) { cnt[i] = 0; cur[i] = 0; }
}

__global__ void k_hist(const int* __restrict__ dst, int* __restrict__ cnt) {
    int e = blockIdx.x * blockDim.x + threadIdx.x;
    if (e < N_EDGES) {
        int d = dst[e];
        if ((unsigned)d < N_NODES) atomicAdd(&cnt[d], 1);
    }
}

// single-block exclusive scan over 10000 counts + dinv = rsqrt(deg), deg=cnt+1 (self-loop)
__global__ void k_scan(const int* __restrict__ cnt, int* __restrict__ rptr,
                       float* __restrict__ dinv) {
    __shared__ int sums[1024];
    int t = threadIdx.x;
    int base_n = t * 10;
    int loc[10];
    int s = 0;
    for (int i = 0; i < 10; i++) {
        int n = base_n + i;
        int c = (n < N_NODES) ? cnt[n] : 0;
        loc[i] = s;
        s += c;
        if (n < N_NODES) dinv[n] = rsqrtf((float)(c + 1));
    }
    sums[t] = s;
    __syncthreads();
    for (int off = 1; off < 1024; off <<= 1) {
        int v = (t >= off) ? sums[t - off] : 0;
        __syncthreads();
        sums[t] += v;
        __syncthreads();
    }
    int basev = (t == 0) ? 0 : sums[t - 1];
    for (int i = 0; i < 10; i++) {
        int n = base_n + i;
        if (n < N_NODES) rptr[n] = basev + loc[i];
    }
    if (t == 0) rptr[N_NODES] = N_EDGES;
}

__global__ void k_fill(const int* __restrict__ src, const int* __restrict__ dst,
                       const int* __restrict__ rptr, int* __restrict__ cur,
                       int* __restrict__ esrc) {
    int e = blockIdx.x * blockDim.x + threadIdx.x;
    if (e < N_EDGES) {
        int d = dst[e];
        if ((unsigned)d >= N_NODES) return;
        int p = rptr[d] + atomicAdd(&cur[d], 1);
        if ((unsigned)p < N_EDGES) esrc[p] = src[e];
    }
}

// F=128 CSR aggregate, float4-vectorized: 32 lanes per node, 8 nodes per 256-thr block.
// out[n] = dinv[n]^2*xw[n] + sum_e dinv[src]*dinv[n]*xw[src] (+ bias).
// 2-deep software pipeline on the esrc->gather dependent chain.
__global__ void k_agg128(const float* __restrict__ xw, const float* __restrict__ dinv,
                         const int* __restrict__ rptr, const int* __restrict__ esrc,
                         const float* __restrict__ bias,
                         float* __restrict__ outf, bf16* __restrict__ outb) {
    int node = blockIdx.x * 8 + (threadIdx.x >> 5);
    int c = threadIdx.x & 31;               // float4 lane: features 4c..4c+3
    float dn = dinv[node];
    const float4v* __restrict__ base = (const float4v*)xw;
    float4v acc = base[(size_t)node * 32 + c];
    float dn2 = dn * dn;
#pragma unroll
    for (int j = 0; j < 4; j++) acc[j] *= dn2;

    int e0 = rptr[node], e1 = rptr[node + 1];
    int e = e0;
    if (e < e1) {
        int s = esrc[e];
        if ((unsigned)s >= N_NODES) s = 0;
        float4v v = base[(size_t)s * 32 + c];
        float w = dinv[s];
        for (++e; e < e1; ++e) {
            int s2 = esrc[e];
            if ((unsigned)s2 >= N_NODES) s2 = 0;
            float4v v2 = base[(size_t)s2 * 32 + c];   // issue next gather early
            float w2 = dinv[s2];
            float ww = dn * w;
#pragma unroll
            for (int j = 0; j < 4; j++) acc[j] += ww * v[j];
            v = v2; w = w2;
        }
        float ww = dn * w;
#pragma unroll
        for (int j = 0; j < 4; j++) acc[j] += ww * v[j];
    }

    if (bias) {
        float4v bv = *(const float4v*)(bias + c * 4);
#pragma unroll
        for (int j = 0; j < 4; j++) acc[j] += bv[j];
    }
    if (outf) *(float4v*)(outf + (size_t)node * 128 + c * 4) = acc;
    if (outb) {
        ushort4v p;
#pragma unroll
        for (int j = 0; j < 4; j++) {
            bf16 t = __float2bfloat16(acc[j]);
            p[j] = *reinterpret_cast<unsigned short*>(&t);
        }
        *(ushort4v*)((unsigned short*)outb + (size_t)node * 128 + c * 4) = p;
    }
}

// out[n,f] = x[n,:] @ W[:,f]  with NT=8 nodes per thread (W traffic /8 vs naive).
// blockDim = F; x-row reads are block-uniform -> one broadcast cacheline per load.
// FUSE: add bias then relu (layer-1 epilogue).
template <int K, int F, bool FUSE>
__global__ void k_linear(const float* __restrict__ x, const float* __restrict__ W,
                         const float* __restrict__ bias, float* __restrict__ out) {
    int n0 = blockIdx.x * 8;
    int t = threadIdx.x;  // feature
    float acc[8];
#pragma unroll
    for (int i = 0; i < 8; i++) acc[i] = 0.f;
    const float* __restrict__ Wf = W + t;
    const float* __restrict__ x0 = x + (size_t)n0 * K;
    for (int k = 0; k < K; k += 4) {
        // 4 consecutive k of each of the 8 rows, uniform addresses
        float4v xr[8];
#pragma unroll
        for (int i = 0; i < 8; i++) xr[i] = *(const float4v*)(x0 + (size_t)i * K + k);
#pragma unroll
        for (int kk = 0; kk < 4; kk++) {
            float w = Wf[(size_t)(k + kk) * F];
#pragma unroll
            for (int i = 0; i < 8; i++) acc[i] += w * xr[i][kk];
        }
    }
    float b = FUSE ? bias[t] : 0.f;
#pragma unroll
    for (int i = 0; i < 8; i++) {
        float v = acc[i] + b;
        if (FUSE) v = fmaxf(v, 0.f);
        out[(size_t)(n0 + i) * F + t] = v;
    }
}

// S = H * H^T, H: [N_NODES,128] bf16, S: [N_NODES,N_NODES] fp32.
// wave computes a 64x64 block (4x4 tiles of 16x16x32 MFMA); block = 4 waves -> 128x128.
// S is symmetric, so we store acc[ti][tj] TRANSPOSED: the MFMA reg axis (4 consecutive
// rows of D) becomes 4 consecutive COLUMNS of S -> global_store_dwordx4 (16 stores/wave
// instead of 64 scalar ones). Coverage is complete because the grid is the full square:
// block (bx,by) writes S[j-range][i-range], and (bx,by) spans all pairs.
__global__ __launch_bounds__(256) void k_sgemm(const bf16* __restrict__ H,
                                               float* __restrict__ S) {
    int w = threadIdx.x >> 6;
    int lane = threadIdx.x & 63;
    int i0 = blockIdx.y * 128 + (w & 1) * 64;
    int j0 = blockIdx.x * 128 + (w >> 1) * 64;
    int l15 = lane & 15;
    int quad = lane >> 4;

    float4v acc[4][4];
    for (int a = 0; a < 4; a++)
        for (int b = 0; b < 4; b++)
            acc[a][b] = (float4v){0.f, 0.f, 0.f, 0.f};

    const short* Hs = (const short*)H;
    for (int kk = 0; kk < 4; kk++) {
        int ko = kk * 32 + quad * 8;
        bshort8 af[4], bfr[4];
#pragma unroll
        for (int t = 0; t < 4; t++) {
            int r = i0 + t * 16 + l15;
            if (r >= N_NODES) r = 0;
            af[t] = *(const bshort8*)(Hs + r * IN_DIM + ko);
            int c = j0 + t * 16 + l15;
            if (c >= N_NODES) c = 0;
            bfr[t] = *(const bshort8*)(Hs + c * IN_DIM + ko);
        }
#pragma unroll
        for (int ti = 0; ti < 4; ti++)
#pragma unroll
            for (int tj = 0; tj < 4; tj++)
                acc[ti][tj] = __builtin_amdgcn_mfma_f32_16x16x32_bf16(
                    af[ti], bfr[tj], acc[ti][tj], 0, 0, 0);
    }

    // transposed (symmetric) store: value D[m][n] = S[i0+m][j0+n] = S[j0+n][i0+m]
#pragma unroll
    for (int ti = 0; ti < 4; ti++) {
        int cbase = i0 + ti * 16 + quad * 4;     // 4 consecutive cols (cbase % 4 == 0)
        if (cbase >= N_NODES) continue;          // N % 4 == 0 -> all-or-nothing
#pragma unroll
        for (int tj = 0; tj < 4; tj++) {
            int row = j0 + tj * 16 + l15;
            if (row >= N_NODES) continue;
            *(float4v*)(S + (size_t)row * N_NODES + cbase) = acc[ti][tj];
        }
    }
}

extern "C" void kernel_launch(void* const* d_in, const int* in_sizes, int n_in,
                              void* d_out, int out_size, void* d_ws, size_t ws_size,
                              hipStream_t stream) {
    const float* h   = (const float*)d_in[0];
    const float* W1a = (const float*)d_in[1];
    const float* b1a = (const float*)d_in[2];
    const float* W2a = (const float*)d_in[3];
    const float* b2a = (const float*)d_in[4];
    const float* W1s = (const float*)d_in[5];
    const float* b1s = (const float*)d_in[6];
    const float* W2s = (const float*)d_in[7];
    const float* b2s = (const float*)d_in[8];
    const int* edge  = (const int*)d_in[9];
    const int* src = edge;
    const int* dst = edge + N_EDGES;

    char* ob = (char*)d_out;
    float* buf1 = (float*)(ob + SC_BUF1);
    float* buf2 = (float*)(ob + SC_BUF2);
    float* aggx = (float*)(ob + SC_AGGX);
    int*   esrc = (int*)(ob + SC_ESRC);
    int*   cnt  = (int*)(ob + SC_CNT);
    int*   cur  = (int*)(ob + SC_CUR);
    int*   rptr = (int*)(ob + SC_RPTR);
    float* dinv = (float*)(ob + SC_DINV);
    bf16*  hs   = (bf16*)(ob + OFF_HS);   // staged in out_h region

    float* out   = (float*)d_out;
    float* out_x = out;                                   // [10000,128]
    float* out_s = out + (size_t)N_NODES * OUT_DIM;       // [10000,10000]
    float* out_h = out_s + (size_t)N_NODES * N_NODES;     // [10000,128]

    // graph prep: degree histogram -> scan -> CSR fill
    k_zero<<<(N_NODES + 255) / 256, 256, 0, stream>>>(cnt, cur);
    k_hist<<<(N_EDGES + 255) / 256, 256, 0, stream>>>(dst, cnt);
    k_scan<<<1, 1024, 0, stream>>>(cnt, rptr, dinv);
    k_fill<<<(N_EDGES + 255) / 256, 256, 0, stream>>>(src, dst, rptr, cur, esrc);

    // shared layer-1 aggregation: aggx = A_norm * x   [10000,128]
    // (GCN conv is linear: A(xW)+b == (Ax)W+b, and Ax is branch-independent)
    k_agg128<<<N_NODES / 8, 256, 0, stream>>>(h, dinv, rptr, esrc,
                                              nullptr, aggx, nullptr);

    for (int br = 0; br < 2; br++) {
        const float* W1 = br ? W1s : W1a;
        const float* b1 = br ? b1s : b1a;
        const float* W2 = br ? W2s : W2a;
        const float* b2 = br ? b2s : b2a;

        // layer 1: h1 = relu(aggx @ W1 + b1)   [10000,256]
        k_linear<IN_DIM, HID_DIM, true>
            <<<N_NODES / 8, HID_DIM, 0, stream>>>(aggx, W1, b1, buf1);
        // layer 2 transform: xw2 = h1 @ W2     [10000,128]
        k_linear<HID_DIM, OUT_DIM, false>
            <<<N_NODES / 8, OUT_DIM, 0, stream>>>(buf1, W2, nullptr, buf2);
        // layer 2 aggregate (+b2) -> final
        if (br == 0)
            k_agg128<<<N_NODES / 8, 256, 0, stream>>>(buf2, dinv, rptr, esrc,
                                                      b2, out_x, nullptr);
        else
            k_agg128<<<N_NODES / 8, 256, 0, stream>>>(buf2, dinv, rptr, esrc,
                                                      b2, nullptr, hs);
    }

    // s_ = h_ @ h_^T  (reads bf16 hs from out_h region, writes fp32 out_s)
    dim3 g((N_NODES + 127) / 128, (N_NODES + 127) / 128);
    k_sgemm<<<g, 256, 0, stream>>>(hs, out_s);

    // third output: h passthrough (overwrites hs staging in out_h)
    hipMemcpyAsync(out_h, h, (size_t)N_NODES * IN_DIM * sizeof(float),
                   hipMemcpyDeviceToDevice, stream);
}

// Round 3
// 693.650 us; speedup vs baseline: 1.0934x; 1.0934x over previous
//
#include <hip/hip_runtime.h>
#include <hip/hip_bf16.h>

typedef __hip_bfloat16 bf16;
typedef __attribute__((ext_vector_type(8))) short bshort8;
typedef __attribute__((ext_vector_type(4))) float float4v;
typedef __attribute__((ext_vector_type(4))) unsigned short ushort4v;

#define N_NODES 10000
#define N_EDGES 320000
#define IN_DIM  128
#define HID_DIM 256
#define OUT_DIM 128

// ---- d_out layout (fp32 elements) ----
// out_x : floats [0          , 1,280,000)    bytes [0          , 5,120,000)
// out_s : floats [1,280,000  , 101,280,000)  bytes [5,120,000  , 405,120,000)
// out_h : floats [101,280,000, 102,560,000)  bytes [405,120,000, 410,240,000)
//
// Scratch lives inside the out_s byte-region (dead before k_sgemm writes it);
// hs (bf16 staging of h_) lives in the out_h region (overwritten by the final
// h-passthrough memcpy AFTER k_sgemm has consumed it). d_ws deliberately unused.
#define SC_BUF1A 5120000ull    // h1 attr   [10000,256] f32 = 10,240,000 B
#define SC_BUF1S 15360000ull   // h1 struct [10000,256] f32 = 10,240,000 B
#define SC_BUF2A 25600000ull   // xw2 attr  [10000,128] f32 =  5,120,000 B
#define SC_BUF2S 30720000ull   // xw2 struct[10000,128] f32 =  5,120,000 B
#define SC_AGGX  35840000ull   // A*x       [10000,128] f32 =  5,120,000 B (branch-shared)
#define SC_ESRC  40960000ull   // 320000 i32 = 1,280,000 B
#define SC_EWT   42240000ull   // 320000 f32 = 1,280,000 B (dinv[src] per CSR slot)
#define SC_CNT   43520000ull   // 10000 i32
#define SC_CUR   43560000ull   // 10000 i32
#define SC_RPTR  43600000ull   // 10001 i32
#define SC_DINV  43640064ull   // 10000 f32 (ends 43,680,064 << 405,120,000)
#define OFF_HS   405120000ull  // 10000x128 bf16 = 2,560,000 B (inside out_h's 5.12 MB)

__global__ void k_zero(int* __restrict__ cnt, int* __restrict__ cur) {
    int i = blockIdx.x * blockDim.x + threadIdx.x;
    if (i < N_NODES) { cnt[i] = 0; cur[i] = 0; }
}

__global__ void k_hist(const int* __restrict__ dst, int* __restrict__ cnt) {
    int e = blockIdx.x * blockDim.x + threadIdx.x;
    if (e < N_EDGES) {
        int d = dst[e];
        if ((unsigned)d < N_NODES) atomicAdd(&cnt[d], 1);
    }
}

// single-block exclusive scan over 10000 counts + dinv = rsqrt(deg), deg=cnt+1 (self-loop)
__global__ void k_scan(const int* __restrict__ cnt, int* __restrict__ rptr,
                       float* __restrict__ dinv) {
    __shared__ int sums[1024];
    int t = threadIdx.x;
    int base_n = t * 10;
    int loc[10];
    int s = 0;
    for (int i = 0; i < 10; i++) {
        int n = base_n + i;
        int c = (n < N_NODES) ? cnt[n] : 0;
        loc[i] = s;
        s += c;
        if (n < N_NODES) dinv[n] = rsqrtf((float)(c + 1));
    }
    sums[t] = s;
    __syncthreads();
    for (int off = 1; off < 1024; off <<= 1) {
        int v = (t >= off) ? sums[t - off] : 0;
        __syncthreads();
        sums[t] += v;
        __syncthreads();
    }
    int basev = (t == 0) ? 0 : sums[t - 1];
    for (int i = 0; i < 10; i++) {
        int n = base_n + i;
        if (n < N_NODES) rptr[n] = basev + loc[i];
    }
    if (t == 0) rptr[N_NODES] = N_EDGES;
}

// CSR fill; also precompute per-slot weight ewt = dinv[src] (kills the dependent
// dinv gather inside the aggregate's critical chain). dinv ready (k_scan ran).
__global__ void k_fill(const int* __restrict__ src, const int* __restrict__ dst,
                       const int* __restrict__ rptr, int* __restrict__ cur,
                       const float* __restrict__ dinv,
                       int* __restrict__ esrc, float* __restrict__ ewt) {
    int e = blockIdx.x * blockDim.x + threadIdx.x;
    if (e < N_EDGES) {
        int d = dst[e];
        if ((unsigned)d >= N_NODES) return;
        int sv = src[e];
        int p = rptr[d] + atomicAdd(&cur[d], 1);
        if ((unsigned)p < N_EDGES) {
            esrc[p] = sv;
            ewt[p] = ((unsigned)sv < N_NODES) ? dinv[sv] : 0.f;
        }
    }
}

// Batched CSR aggregate core: 32 lanes per node (float4 lane = 4 features),
// 8-deep edge batches -> 8 independent 512B row-gathers in flight (MLP=8).
// Padding lanes use weight 0 (exact). Returns un-biased accumulation.
__device__ __forceinline__ float4v agg_core(const float* __restrict__ xw,
                                            const float* __restrict__ dinv,
                                            const int* __restrict__ rptr,
                                            const int* __restrict__ esrc,
                                            const float* __restrict__ ewt,
                                            int node, int c) {
    float dn = dinv[node];
    const float4v* __restrict__ base = (const float4v*)xw;
    float4v acc = base[node * 32 + c];
    float dn2 = dn * dn;
#pragma unroll
    for (int j = 0; j < 4; j++) acc[j] *= dn2;

    int e0 = rptr[node], e1 = rptr[node + 1];
    for (int e = e0; e < e1; e += 8) {
        int idx[8];
        float wt[8];
#pragma unroll
        for (int u = 0; u < 8; u++) {
            int ee = e + u;
            int eec = (ee < N_EDGES) ? ee : (N_EDGES - 1);
            int s = esrc[eec];
            float wv = ewt[eec];
            if ((unsigned)s >= N_NODES) s = 0;
            idx[u] = s;
            wt[u] = (ee < e1) ? wv : 0.f;
        }
        float4v v[8];
#pragma unroll
        for (int u = 0; u < 8; u++) v[u] = base[idx[u] * 32 + c];
#pragma unroll
        for (int u = 0; u < 8; u++) {
            float ww = dn * wt[u];
#pragma unroll
            for (int j = 0; j < 4; j++) acc[j] += ww * v[u][j];
        }
    }
    return acc;
}

// aggx = A_norm * x (no bias), fp32 out. 8 nodes / 256-thr block.
__global__ void k_agg_one(const float* __restrict__ xw, const float* __restrict__ dinv,
                          const int* __restrict__ rptr, const int* __restrict__ esrc,
                          const float* __restrict__ ewt, float* __restrict__ outf) {
    int node = blockIdx.x * 8 + (threadIdx.x >> 5);
    int c = threadIdx.x & 31;
    float4v acc = agg_core(xw, dinv, rptr, esrc, ewt, node, c);
    *(float4v*)(outf + node * 128 + c * 4) = acc;
}

// final aggregates for both branches in one dispatch: y=0 -> out_x fp32 (+b2a),
// y=1 -> hs bf16 (+b2s).
__global__ void k_agg_fin(const float* __restrict__ xwa, const float* __restrict__ xws,
                          const float* __restrict__ dinv, const int* __restrict__ rptr,
                          const int* __restrict__ esrc, const float* __restrict__ ewt,
                          const float* __restrict__ ba, const float* __restrict__ bs,
                          float* __restrict__ out_x, bf16* __restrict__ hs) {
    int br = blockIdx.y;
    const float* xw = br ? xws : xwa;
    const float* bias = br ? bs : ba;
    int node = blockIdx.x * 8 + (threadIdx.x >> 5);
    int c = threadIdx.x & 31;
    float4v acc = agg_core(xw, dinv, rptr, esrc, ewt, node, c);
    float4v bv = *(const float4v*)(bias + c * 4);
#pragma unroll
    for (int j = 0; j < 4; j++) acc[j] += bv[j];
    if (br == 0) {
        *(float4v*)(out_x + node * 128 + c * 4) = acc;
    } else {
        ushort4v p;
#pragma unroll
        for (int j = 0; j < 4; j++) {
            bf16 t = __float2bfloat16(acc[j]);
            p[j] = *reinterpret_cast<unsigned short*>(&t);
        }
        *(ushort4v*)((unsigned short*)hs + node * 128 + c * 4) = p;
    }
}

// out[n,f] = x[n,:] @ W[:,f], NT=8 nodes/thread; both branches via blockIdx.y.
// x-row loads are block-uniform (scalar-cache path); W loads coalesced over t.
// FUSE: +bias, relu (layer-1 epilogue).
template <int K, int F, bool FUSE>
__global__ void k_linear(const float* __restrict__ xa, const float* __restrict__ xs,
                         const float* __restrict__ Wa, const float* __restrict__ Ws,
                         const float* __restrict__ ba, const float* __restrict__ bs,
                         float* __restrict__ oa, float* __restrict__ os) {
    const float* __restrict__ x = blockIdx.y ? xs : xa;
    const float* __restrict__ W = blockIdx.y ? Ws : Wa;
    const float* __restrict__ bias = blockIdx.y ? bs : ba;
    float* __restrict__ out = blockIdx.y ? os : oa;

    int n0 = blockIdx.x * 8;
    int t = threadIdx.x;  // feature
    float acc[8];
#pragma unroll
    for (int i = 0; i < 8; i++) acc[i] = 0.f;
    const float* __restrict__ Wf = W + t;
    const float* __restrict__ x0 = x + (size_t)n0 * K;
    for (int k = 0; k < K; k += 4) {
        float4v xr[8];
#pragma unroll
        for (int i = 0; i < 8; i++) xr[i] = *(const float4v*)(x0 + (size_t)i * K + k);
#pragma unroll
        for (int kk = 0; kk < 4; kk++) {
            float w = Wf[(size_t)(k + kk) * F];
#pragma unroll
            for (int i = 0; i < 8; i++) acc[i] += w * xr[i][kk];
        }
    }
    float b = FUSE ? bias[t] : 0.f;
#pragma unroll
    for (int i = 0; i < 8; i++) {
        float v = acc[i] + b;
        if (FUSE) v = fmaxf(v, 0.f);
        out[(size_t)(n0 + i) * F + t] = v;
    }
}

// S = H * H^T, H: [N_NODES,128] bf16, S: [N_NODES,N_NODES] fp32.
// wave computes a 64x64 block (4x4 tiles of 16x16x32 MFMA); block = 4 waves -> 128x128.
// S is symmetric: store acc[ti][tj] TRANSPOSED so the MFMA reg axis becomes 4
// consecutive COLUMNS of S -> global_store_dwordx4 (16 stores/wave vs 64 scalar).
// Coverage complete: block (bx,by) writes S[j-range][i-range] over the full grid square.
__global__ __launch_bounds__(256) void k_sgemm(const bf16* __restrict__ H,
                                               float* __restrict__ S) {
    int w = threadIdx.x >> 6;
    int lane = threadIdx.x & 63;
    int i0 = blockIdx.y * 128 + (w & 1) * 64;
    int j0 = blockIdx.x * 128 + (w >> 1) * 64;
    int l15 = lane & 15;
    int quad = lane >> 4;

    float4v acc[4][4];
    for (int a = 0; a < 4; a++)
        for (int b = 0; b < 4; b++)
            acc[a][b] = (float4v){0.f, 0.f, 0.f, 0.f};

    const short* Hs = (const short*)H;
    for (int kk = 0; kk < 4; kk++) {
        int ko = kk * 32 + quad * 8;
        bshort8 af[4], bfr[4];
#pragma unroll
        for (int t = 0; t < 4; t++) {
            int r = i0 + t * 16 + l15;
            if (r >= N_NODES) r = 0;
            af[t] = *(const bshort8*)(Hs + r * IN_DIM + ko);
            int c = j0 + t * 16 + l15;
            if (c >= N_NODES) c = 0;
            bfr[t] = *(const bshort8*)(Hs + c * IN_DIM + ko);
        }
#pragma unroll
        for (int ti = 0; ti < 4; ti++)
#pragma unroll
            for (int tj = 0; tj < 4; tj++)
                acc[ti][tj] = __builtin_amdgcn_mfma_f32_16x16x32_bf16(
                    af[ti], bfr[tj], acc[ti][tj], 0, 0, 0);
    }

    // transposed (symmetric) store: D[m][n] = S[i0+m][j0+n] = S[j0+n][i0+m]
#pragma unroll
    for (int ti = 0; ti < 4; ti++) {
        int cbase = i0 + ti * 16 + quad * 4;     // 4 consecutive cols (cbase % 4 == 0)
        if (cbase >= N_NODES) continue;          // N % 4 == 0 -> all-or-nothing
#pragma unroll
        for (int tj = 0; tj < 4; tj++) {
            int row = j0 + tj * 16 + l15;
            if (row >= N_NODES) continue;
            *(float4v*)(S + (size_t)row * N_NODES + cbase) = acc[ti][tj];
        }
    }
}

extern "C" void kernel_launch(void* const* d_in, const int* in_sizes, int n_in,
                              void* d_out, int out_size, void* d_ws, size_t ws_size,
                              hipStream_t stream) {
    const float* h   = (const float*)d_in[0];
    const float* W1a = (const float*)d_in[1];
    const float* b1a = (const float*)d_in[2];
    const float* W2a = (const float*)d_in[3];
    const float* b2a = (const float*)d_in[4];
    const float* W1s = (const float*)d_in[5];
    const float* b1s = (const float*)d_in[6];
    const float* W2s = (const float*)d_in[7];
    const float* b2s = (const float*)d_in[8];
    const int* edge  = (const int*)d_in[9];
    const int* src = edge;
    const int* dst = edge + N_EDGES;

    char* ob = (char*)d_out;
    float* buf1a = (float*)(ob + SC_BUF1A);
    float* buf1s = (float*)(ob + SC_BUF1S);
    float* buf2a = (float*)(ob + SC_BUF2A);
    float* buf2s = (float*)(ob + SC_BUF2S);
    float* aggx  = (float*)(ob + SC_AGGX);
    int*   esrc  = (int*)(ob + SC_ESRC);
    float* ewt   = (float*)(ob + SC_EWT);
    int*   cnt   = (int*)(ob + SC_CNT);
    int*   cur   = (int*)(ob + SC_CUR);
    int*   rptr  = (int*)(ob + SC_RPTR);
    float* dinv  = (float*)(ob + SC_DINV);
    bf16*  hs    = (bf16*)(ob + OFF_HS);   // staged in out_h region

    float* out   = (float*)d_out;
    float* out_x = out;                                   // [10000,128]
    float* out_s = out + (size_t)N_NODES * OUT_DIM;       // [10000,10000]
    float* out_h = out_s + (size_t)N_NODES * N_NODES;     // [10000,128]

    // graph prep: degree histogram -> scan -> CSR fill (+ per-edge weight)
    k_zero<<<(N_NODES + 255) / 256, 256, 0, stream>>>(cnt, cur);
    k_hist<<<(N_EDGES + 255) / 256, 256, 0, stream>>>(dst, cnt);
    k_scan<<<1, 1024, 0, stream>>>(cnt, rptr, dinv);
    k_fill<<<(N_EDGES + 255) / 256, 256, 0, stream>>>(src, dst, rptr, cur,
                                                      dinv, esrc, ewt);

    // shared layer-1 aggregation: aggx = A_norm * x (GCN conv is linear:
    // A(xW)+b == (Ax)W+b, and Ax is branch-independent)
    k_agg_one<<<N_NODES / 8, 256, 0, stream>>>(h, dinv, rptr, esrc, ewt, aggx);

    // both branches in one dispatch per layer (blockIdx.y = branch)
    // layer 1: h1 = relu(aggx @ W1 + b1)  [10000,256] x2
    k_linear<IN_DIM, HID_DIM, true>
        <<<dim3(N_NODES / 8, 2), HID_DIM, 0, stream>>>(
            aggx, aggx, W1a, W1s, b1a, b1s, buf1a, buf1s);
    // layer 2 transform: xw2 = h1 @ W2   [10000,128] x2
    k_linear<HID_DIM, OUT_DIM, false>
        <<<dim3(N_NODES / 8, 2), OUT_DIM, 0, stream>>>(
            buf1a, buf1s, W2a, W2s, nullptr, nullptr, buf2a, buf2s);
    // layer 2 aggregate + bias -> out_x (fp32) / hs (bf16)
    k_agg_fin<<<dim3(N_NODES / 8, 2), 256, 0, stream>>>(
        buf2a, buf2s, dinv, rptr, esrc, ewt, b2a, b2s, out_x, hs);

    // s_ = h_ @ h_^T  (reads bf16 hs from out_h region, writes fp32 out_s)
    dim3 g((N_NODES + 127) / 128, (N_NODES + 127) / 128);
    k_sgemm<<<g, 256, 0, stream>>>(hs, out_s);

    // third output: h passthrough (overwrites hs staging in out_h)
    hipMemcpyAsync(out_h, h, (size_t)N_NODES * IN_DIM * sizeof(float),
                   hipMemcpyDeviceToDevice, stream);
}

// Round 4
// 681.237 us; speedup vs baseline: 1.1133x; 1.0182x over previous
//
#include <hip/hip_runtime.h>
#include <hip/hip_bf16.h>

typedef __hip_bfloat16 bf16;
typedef __attribute__((ext_vector_type(8))) short bshort8;
typedef __attribute__((ext_vector_type(4))) float float4v;
typedef __attribute__((ext_vector_type(2))) float float2v;
typedef __attribute__((ext_vector_type(2))) unsigned short ushort2v;

#define N_NODES 10000
#define N_EDGES 320000
#define IN_DIM  128
#define HID_DIM 256
#define OUT_DIM 128

// ---- d_out layout (fp32 elements) ----
// out_x : floats [0          , 1,280,000)    bytes [0          , 5,120,000)
// out_s : floats [1,280,000  , 101,280,000)  bytes [5,120,000  , 405,120,000)
// out_h : floats [101,280,000, 102,560,000)  bytes [405,120,000, 410,240,000)
//
// Scratch lives inside the out_s byte-region (dead before k_sgemm writes it);
// hs (bf16 staging of h_) lives in the out_h region (overwritten by the final
// h-passthrough memcpy AFTER k_sgemm has consumed it). d_ws deliberately unused.
#define SC_AGGX  5120000ull    // A*x       [10000,128] f32 = 5,120,000 B (branch-shared)
#define SC_BUF2A 10240000ull   // xw2 attr  [10000,128] f32 = 5,120,000 B
#define SC_BUF2S 15360000ull   // xw2 struct[10000,128] f32 = 5,120,000 B
#define SC_ESRC  20480000ull   // 320000 i32 = 1,280,000 B
#define SC_EWT   21760000ull   // 320000 f32 = 1,280,000 B (dinv[src] per CSR slot)
#define SC_CNT   23040000ull   // 10000 i32
#define SC_CUR   23080000ull   // 10000 i32
#define SC_RPTR  23120000ull   // 10001 i32
#define SC_DINV  23160064ull   // 10000 f32 (ends 23,200,064 << 405,120,000)
#define OFF_HS   405120000ull  // 10000x128 bf16 = 2,560,000 B (inside out_h's 5.12 MB)

__global__ void k_zero(int* __restrict__ cnt, int* __restrict__ cur) {
    int i = blockIdx.x * blockDim.x + threadIdx.x;
    if (i < N_NODES) { cnt[i] = 0; cur[i] = 0; }
}

__global__ void k_hist(const int* __restrict__ dst, int* __restrict__ cnt) {
    int e = blockIdx.x * blockDim.x + threadIdx.x;
    if (e < N_EDGES) {
        int d = dst[e];
        if ((unsigned)d < N_NODES) atomicAdd(&cnt[d], 1);
    }
}

// single-block exclusive scan over 10000 counts + dinv = rsqrt(deg), deg=cnt+1 (self-loop)
__global__ void k_scan(const int* __restrict__ cnt, int* __restrict__ rptr,
                       float* __restrict__ dinv) {
    __shared__ int sums[1024];
    int t = threadIdx.x;
    int base_n = t * 10;
    int loc[10];
    int s = 0;
    for (int i = 0; i < 10; i++) {
        int n = base_n + i;
        int c = (n < N_NODES) ? cnt[n] : 0;
        loc[i] = s;
        s += c;
        if (n < N_NODES) dinv[n] = rsqrtf((float)(c + 1));
    }
    sums[t] = s;
    __syncthreads();
    for (int off = 1; off < 1024; off <<= 1) {
        int v = (t >= off) ? sums[t - off] : 0;
        __syncthreads();
        sums[t] += v;
        __syncthreads();
    }
    int basev = (t == 0) ? 0 : sums[t - 1];
    for (int i = 0; i < 10; i++) {
        int n = base_n + i;
        if (n < N_NODES) rptr[n] = basev + loc[i];
    }
    if (t == 0) rptr[N_NODES] = N_EDGES;
}

// CSR fill; also precompute per-slot weight ewt = dinv[src] (keeps the dependent
// dinv gather out of the aggregate's critical chain). dinv ready (k_scan ran).
__global__ void k_fill(const int* __restrict__ src, const int* __restrict__ dst,
                       const int* __restrict__ rptr, int* __restrict__ cur,
                       const float* __restrict__ dinv,
                       int* __restrict__ esrc, float* __restrict__ ewt) {
    int e = blockIdx.x * blockDim.x + threadIdx.x;
    if (e < N_EDGES) {
        int d = dst[e];
        if ((unsigned)d >= N_NODES) return;
        int sv = src[e];
        int p = rptr[d] + atomicAdd(&cur[d], 1);
        if ((unsigned)p < N_EDGES) {
            esrc[p] = sv;
            ewt[p] = ((unsigned)sv < N_NODES) ? dinv[sv] : 0.f;
        }
    }
}

// ---- aggregate core v3: ONE NODE PER WAVE (float2 lane -> 64x8B = one 512B row).
// Loop bounds wave-uniform (no divergence); 8-deep gather batches with an explicit
// double-buffered idx/wt pipeline: next batch's idx/wt loads are issued BETWEEN this
// batch's gathers and its FMAs, so they overlap the vmcnt wait. Padding weight 0.
__device__ __forceinline__ float2v agg_core(const float* __restrict__ xw,
                                            const float* __restrict__ dinv,
                                            const int* __restrict__ rptr,
                                            const int* __restrict__ esrc,
                                            const float* __restrict__ ewt,
                                            int node, int lane) {
    const float2v* __restrict__ base = (const float2v*)xw;  // row stride 64 float2
    float dn = dinv[node];
    float2v acc = base[node * 64 + lane];
    float dn2 = dn * dn;
    acc[0] *= dn2; acc[1] *= dn2;

    int e0 = rptr[node], e1 = rptr[node + 1];

    int idxA[8]; float wtA[8];
#pragma unroll
    for (int u = 0; u < 8; u++) {                   // prologue: batch 0 idx/wt
        int ee = e0 + u;
        int eec = (ee < N_EDGES) ? ee : (N_EDGES - 1);
        int s = esrc[eec];
        float wv = ewt[eec];
        idxA[u] = ((unsigned)s < N_NODES) ? s : 0;
        wtA[u] = (ee < e1) ? wv : 0.f;
    }

    for (int eb = e0; eb < e1; eb += 8) {
        float2v v[8];
#pragma unroll
        for (int u = 0; u < 8; u++) v[u] = base[idxA[u] * 64 + lane];  // gathers
        int nb = eb + 8;
        int pb = (nb < e1) ? nb : eb;               // prefetch base (safe re-read if last)
        int idxB[8]; float wtB[8];
#pragma unroll
        for (int u = 0; u < 8; u++) {               // prefetch next batch (in flight
            int ee = pb + u;                        //  across the gather vmcnt wait)
            int eec = (ee < N_EDGES) ? ee : (N_EDGES - 1);
            int s = esrc[eec];
            float wv = ewt[eec];
            idxB[u] = ((unsigned)s < N_NODES) ? s : 0;
            wtB[u] = (ee < e1) ? wv : 0.f;
        }
#pragma unroll
        for (int u = 0; u < 8; u++) {
            float ww = dn * wtA[u];
            acc[0] += ww * v[u][0];
            acc[1] += ww * v[u][1];
        }
#pragma unroll
        for (int u = 0; u < 8; u++) { idxA[u] = idxB[u]; wtA[u] = wtB[u]; }
    }
    return acc;
}

// aggx = A_norm * x (no bias). 4 nodes (waves) per 256-thr block.
__global__ void k_agg_one(const float* __restrict__ xw, const float* __restrict__ dinv,
                          const int* __restrict__ rptr, const int* __restrict__ esrc,
                          const float* __restrict__ ewt, float* __restrict__ outf) {
    int node = blockIdx.x * 4 + (threadIdx.x >> 6);
    int lane = threadIdx.x & 63;
    float2v acc = agg_core(xw, dinv, rptr, esrc, ewt, node, lane);
    *(float2v*)(outf + node * 128 + lane * 2) = acc;
}

// final aggregates, both branches in one dispatch: y=0 -> out_x fp32 (+b2a),
// y=1 -> hs bf16 (+b2s).
__global__ void k_agg_fin(const float* __restrict__ xwa, const float* __restrict__ xws,
                          const float* __restrict__ dinv, const int* __restrict__ rptr,
                          const int* __restrict__ esrc, const float* __restrict__ ewt,
                          const float* __restrict__ ba, const float* __restrict__ bs,
                          float* __restrict__ out_x, bf16* __restrict__ hs) {
    int br = blockIdx.y;
    const float* xw = br ? xws : xwa;
    const float* bias = br ? bs : ba;
    int node = blockIdx.x * 4 + (threadIdx.x >> 6);
    int lane = threadIdx.x & 63;
    float2v acc = agg_core(xw, dinv, rptr, esrc, ewt, node, lane);
    float2v bv = *(const float2v*)(bias + lane * 2);
    acc[0] += bv[0]; acc[1] += bv[1];
    if (br == 0) {
        *(float2v*)(out_x + node * 128 + lane * 2) = acc;
    } else {
        ushort2v p;
        bf16 t0 = __float2bfloat16(acc[0]);
        bf16 t1 = __float2bfloat16(acc[1]);
        p[0] = *reinterpret_cast<unsigned short*>(&t0);
        p[1] = *reinterpret_cast<unsigned short*>(&t1);
        *(ushort2v*)((unsigned short*)hs + node * 128 + lane * 2) = p;
    }
}

// Fused 2-layer MLP per block of 8 nodes, both branches via blockIdx.y:
//   phase1: h1[8][256] = relu(aggx[8 nodes][128] @ W1 + b1)  -> LDS (8 KB)
//   phase2: xw2[8][128] = h1 @ W2                            -> buf2
// Saves the 20 MB h1 round-trip + one launch. LDS reads in phase2 are wave-uniform
// broadcasts (all lanes same address) -> conflict-free.
__global__ __launch_bounds__(256) void k_mlp(const float* __restrict__ aggx,
                                             const float* __restrict__ W1a,
                                             const float* __restrict__ W1s,
                                             const float* __restrict__ b1a,
                                             const float* __restrict__ b1s,
                                             const float* __restrict__ W2a,
                                             const float* __restrict__ W2s,
                                             float* __restrict__ o2a,
                                             float* __restrict__ o2s) {
    const float* __restrict__ W1 = blockIdx.y ? W1s : W1a;
    const float* __restrict__ b1 = blockIdx.y ? b1s : b1a;
    const float* __restrict__ W2 = blockIdx.y ? W2s : W2a;
    float* __restrict__ out = blockIdx.y ? o2s : o2a;

    __shared__ float h1[8][HID_DIM];  // 8 KB
    int t = threadIdx.x;
    int n0 = blockIdx.x * 8;

    // phase 1: t = hidden feature
    {
        float acc[8];
#pragma unroll
        for (int i = 0; i < 8; i++) acc[i] = 0.f;
        const float* __restrict__ Wf = W1 + t;
        const float* __restrict__ x0 = aggx + (size_t)n0 * IN_DIM;
        for (int k = 0; k < IN_DIM; k += 4) {
            float4v xr[8];
#pragma unroll
            for (int i = 0; i < 8; i++)
                xr[i] = *(const float4v*)(x0 + (size_t)i * IN_DIM + k);
#pragma unroll
            for (int kk = 0; kk < 4; kk++) {
                float w = Wf[(size_t)(k + kk) * HID_DIM];
#pragma unroll
                for (int i = 0; i < 8; i++) acc[i] += w * xr[i][kk];
            }
        }
        float b = b1[t];
#pragma unroll
        for (int i = 0; i < 8; i++) h1[i][t] = fmaxf(acc[i] + b, 0.f);
    }
    __syncthreads();

    // phase 2: f = t&127 output feature, half = t>>7 selects nodes 0-3 / 4-7
    {
        int f = t & 127;
        int half = t >> 7;
        float acc[4];
#pragma unroll
        for (int i = 0; i < 4; i++) acc[i] = 0.f;
        const float* __restrict__ Wf = W2 + f;
#pragma unroll 4
        for (int k = 0; k < HID_DIM; k++) {
            float w = Wf[(size_t)k * OUT_DIM];
#pragma unroll
            for (int i = 0; i < 4; i++) acc[i] += w * h1[half * 4 + i][k];
        }
#pragma unroll
        for (int i = 0; i < 4; i++)
            out[(size_t)(n0 + half * 4 + i) * OUT_DIM + f] = acc[i];
    }
}

// S = H * H^T, H: [N_NODES,128] bf16, S: [N_NODES,N_NODES] fp32.
// wave computes a 64x64 block (4x4 tiles of 16x16x32 MFMA); block = 4 waves -> 128x128.
// S is symmetric: store acc[ti][tj] TRANSPOSED so the MFMA reg axis becomes 4
// consecutive COLUMNS of S -> 16 dwordx4 stores/wave, each covering 16 full 64B lines.
// NONTEMPORAL stores: the 400 MB S-stream bypasses L2 so the 2.5 MB hs panel stays
// L2-resident for every block's loads.
__global__ __launch_bounds__(256) void k_sgemm(const bf16* __restrict__ H,
                                               float* __restrict__ S) {
    int w = threadIdx.x >> 6;
    int lane = threadIdx.x & 63;
    int i0 = blockIdx.y * 128 + (w & 1) * 64;
    int j0 = blockIdx.x * 128 + (w >> 1) * 64;
    int l15 = lane & 15;
    int quad = lane >> 4;

    float4v acc[4][4];
    for (int a = 0; a < 4; a++)
        for (int b = 0; b < 4; b++)
            acc[a][b] = (float4v){0.f, 0.f, 0.f, 0.f};

    const short* Hs = (const short*)H;
    for (int kk = 0; kk < 4; kk++) {
        int ko = kk * 32 + quad * 8;
        bshort8 af[4], bfr[4];
#pragma unroll
        for (int t = 0; t < 4; t++) {
            int r = i0 + t * 16 + l15;
            if (r >= N_NODES) r = 0;
            af[t] = *(const bshort8*)(Hs + r * IN_DIM + ko);
            int c = j0 + t * 16 + l15;
            if (c >= N_NODES) c = 0;
            bfr[t] = *(const bshort8*)(Hs + c * IN_DIM + ko);
        }
#pragma unroll
        for (int ti = 0; ti < 4; ti++)
#pragma unroll
            for (int tj = 0; tj < 4; tj++)
                acc[ti][tj] = __builtin_amdgcn_mfma_f32_16x16x32_bf16(
                    af[ti], bfr[tj], acc[ti][tj], 0, 0, 0);
    }

    // transposed (symmetric) store: D[m][n] = S[i0+m][j0+n] = S[j0+n][i0+m]
#pragma unroll
    for (int ti = 0; ti < 4; ti++) {
        int cbase = i0 + ti * 16 + quad * 4;     // 4 consecutive cols (cbase % 4 == 0)
        if (cbase >= N_NODES) continue;          // N % 4 == 0 -> all-or-nothing
#pragma unroll
        for (int tj = 0; tj < 4; tj++) {
            int row = j0 + tj * 16 + l15;
            if (row >= N_NODES) continue;
            __builtin_nontemporal_store(acc[ti][tj],
                                        (float4v*)(S + (size_t)row * N_NODES + cbase));
        }
    }
}

extern "C" void kernel_launch(void* const* d_in, const int* in_sizes, int n_in,
                              void* d_out, int out_size, void* d_ws, size_t ws_size,
                              hipStream_t stream) {
    const float* h   = (const float*)d_in[0];
    const float* W1a = (const float*)d_in[1];
    const float* b1a = (const float*)d_in[2];
    const float* W2a = (const float*)d_in[3];
    const float* b2a = (const float*)d_in[4];
    const float* W1s = (const float*)d_in[5];
    const float* b1s = (const float*)d_in[6];
    const float* W2s = (const float*)d_in[7];
    const float* b2s = (const float*)d_in[8];
    const int* edge  = (const int*)d_in[9];
    const int* src = edge;
    const int* dst = edge + N_EDGES;

    char* ob = (char*)d_out;
    float* aggx  = (float*)(ob + SC_AGGX);
    float* buf2a = (float*)(ob + SC_BUF2A);
    float* buf2s = (float*)(ob + SC_BUF2S);
    int*   esrc  = (int*)(ob + SC_ESRC);
    float* ewt   = (float*)(ob + SC_EWT);
    int*   cnt   = (int*)(ob + SC_CNT);
    int*   cur   = (int*)(ob + SC_CUR);
    int*   rptr  = (int*)(ob + SC_RPTR);
    float* dinv  = (float*)(ob + SC_DINV);
    bf16*  hs    = (bf16*)(ob + OFF_HS);   // staged in out_h region

    float* out   = (float*)d_out;
    float* out_x = out;                                   // [10000,128]
    float* out_s = out + (size_t)N_NODES * OUT_DIM;       // [10000,10000]
    float* out_h = out_s + (size_t)N_NODES * N_NODES;     // [10000,128]

    // graph prep: degree histogram -> scan -> CSR fill (+ per-edge weight)
    k_zero<<<(N_NODES + 255) / 256, 256, 0, stream>>>(cnt, cur);
    k_hist<<<(N_EDGES + 255) / 256, 256, 0, stream>>>(dst, cnt);
    k_scan<<<1, 1024, 0, stream>>>(cnt, rptr, dinv);
    k_fill<<<(N_EDGES + 255) / 256, 256, 0, stream>>>(src, dst, rptr, cur,
                                                      dinv, esrc, ewt);

    // shared layer-1 aggregation: aggx = A_norm * x (GCN conv is linear:
    // A(xW)+b == (Ax)W+b, and Ax is branch-independent)
    k_agg_one<<<N_NODES / 4, 256, 0, stream>>>(h, dinv, rptr, esrc, ewt, aggx);

    // fused MLP: relu(aggx@W1+b1)@W2 for both branches (blockIdx.y)
    k_mlp<<<dim3(N_NODES / 8, 2), 256, 0, stream>>>(
        aggx, W1a, W1s, b1a, b1s, W2a, W2s, buf2a, buf2s);

    // layer 2 aggregate + bias -> out_x (fp32) / hs (bf16)
    k_agg_fin<<<dim3(N_NODES / 4, 2), 256, 0, stream>>>(
        buf2a, buf2s, dinv, rptr, esrc, ewt, b2a, b2s, out_x, hs);

    // s_ = h_ @ h_^T  (reads bf16 hs from out_h region, writes fp32 out_s)
    dim3 g((N_NODES + 127) / 128, (N_NODES + 127) / 128);
    k_sgemm<<<g, 256, 0, stream>>>(hs, out_s);

    // third output: h passthrough (overwrites hs staging in out_h)
    hipMemcpyAsync(out_h, h, (size_t)N_NODES * IN_DIM * sizeof(float),
                   hipMemcpyDeviceToDevice, stream);
}

// Round 5
// 670.550 us; speedup vs baseline: 1.1310x; 1.0159x over previous
//
#include <hip/hip_runtime.h>
#include <hip/hip_bf16.h>

typedef __hip_bfloat16 bf16;
typedef __attribute__((ext_vector_type(8))) short bshort8;
typedef __attribute__((ext_vector_type(4))) float float4v;
typedef __attribute__((ext_vector_type(4))) unsigned short ushort4v;

#define N_NODES 10000
#define N_EDGES 320000
#define IN_DIM  128
#define HID_DIM 256
#define OUT_DIM 128

// ---- d_out layout (fp32 elements) ----
// out_x : floats [0          , 1,280,000)    bytes [0          , 5,120,000)
// out_s : floats [1,280,000  , 101,280,000)  bytes [5,120,000  , 405,120,000)
// out_h : floats [101,280,000, 102,560,000)  bytes [405,120,000, 410,240,000)
//
// Scratch lives inside the out_s byte-region (dead before k_sgemm writes it);
// hs (bf16 staging of h_) lives in the out_h region (overwritten by the final
// h-passthrough memcpy AFTER k_sgemm has consumed it). d_ws deliberately unused.
#define SC_AGGX  5120000ull    // A*x  [10000,128] f32          =  5,120,000 B
#define SC_BUFI  10240000ull   // xw2  [10000,2,128] f32 interleaved = 10,240,000 B
#define SC_ESRC  20480000ull   // 320000 i32 = 1,280,000 B
#define SC_EWT   21760000ull   // 320000 f32 = 1,280,000 B (dinv[src] per CSR slot)
#define SC_CNT   23040000ull   // 10000 i32
#define SC_CUR   23080000ull   // 10000 i32
#define SC_RPTR  23120000ull   // 10001 i32
#define SC_DINV  23160064ull   // 10000 f32 (ends 23,200,064 << 405,120,000)
#define OFF_HS   405120000ull  // 10000x128 bf16 = 2,560,000 B (inside out_h's 5.12 MB)

__global__ void k_zero(int* __restrict__ cnt, int* __restrict__ cur) {
    int i = blockIdx.x * blockDim.x + threadIdx.x;
    if (i < N_NODES) { cnt[i] = 0; cur[i] = 0; }
}

__global__ void k_hist(const int* __restrict__ dst, int* __restrict__ cnt) {
    int e = blockIdx.x * blockDim.x + threadIdx.x;
    if (e < N_EDGES) {
        int d = dst[e];
        if ((unsigned)d < N_NODES) atomicAdd(&cnt[d], 1);
    }
}

// single-block exclusive scan over 10000 counts + dinv = rsqrt(deg), deg=cnt+1 (self-loop)
__global__ void k_scan(const int* __restrict__ cnt, int* __restrict__ rptr,
                       float* __restrict__ dinv) {
    __shared__ int sums[1024];
    int t = threadIdx.x;
    int base_n = t * 10;
    int loc[10];
    int s = 0;
    for (int i = 0; i < 10; i++) {
        int n = base_n + i;
        int c = (n < N_NODES) ? cnt[n] : 0;
        loc[i] = s;
        s += c;
        if (n < N_NODES) dinv[n] = rsqrtf((float)(c + 1));
    }
    sums[t] = s;
    __syncthreads();
    for (int off = 1; off < 1024; off <<= 1) {
        int v = (t >= off) ? sums[t - off] : 0;
        __syncthreads();
        sums[t] += v;
        __syncthreads();
    }
    int basev = (t == 0) ? 0 : sums[t - 1];
    for (int i = 0; i < 10; i++) {
        int n = base_n + i;
        if (n < N_NODES) rptr[n] = basev + loc[i];
    }
    if (t == 0) rptr[N_NODES] = N_EDGES;
}

// CSR fill; also precompute per-slot weight ewt = dinv[src] (keeps the dependent
// dinv gather out of the aggregate's critical chain). dinv ready (k_scan ran).
__global__ void k_fill(const int* __restrict__ src, const int* __restrict__ dst,
                       const int* __restrict__ rptr, int* __restrict__ cur,
                       const float* __restrict__ dinv,
                       int* __restrict__ esrc, float* __restrict__ ewt) {
    int e = blockIdx.x * blockDim.x + threadIdx.x;
    if (e < N_EDGES) {
        int d = dst[e];
        if ((unsigned)d >= N_NODES) return;
        int sv = src[e];
        int p = rptr[d] + atomicAdd(&cur[d], 1);
        if ((unsigned)p < N_EDGES) {
            esrc[p] = sv;
            ewt[p] = ((unsigned)sv < N_NODES) ? dinv[sv] : 0.f;
        }
    }
}

// aggx = A_norm * x. One node per wave; HALF-WAVE per edge: lanes 0-31 own edge
// 2u, lanes 32-63 edge 2u+1 (float4 lane -> 32x16B = one 512B row per half-wave).
// A batch of 8 slots = 16 edges in flight -> avg chains/node = deg/16 ~ 2.
// Double-buffered idx/wt prefetch overlaps the gather vmcnt wait. Padding wt=0.
// Cross-half reduction via __shfl_xor(32) at the end.
__global__ void k_agg_one(const float* __restrict__ xw, const float* __restrict__ dinv,
                          const int* __restrict__ rptr, const int* __restrict__ esrc,
                          const float* __restrict__ ewt, float* __restrict__ outf) {
    int node = blockIdx.x * 4 + (threadIdx.x >> 6);
    int lane = threadIdx.x & 63;
    int epar = lane >> 5;   // edge parity within a slot
    int l32 = lane & 31;    // float4 column
    const float4v* __restrict__ x4 = (const float4v*)xw;  // row = 32 float4
    float dn = dinv[node];
    int e0 = rptr[node], e1 = rptr[node + 1];

    float4v acc;
    if (epar == 0) {
        acc = x4[node * 32 + l32];
        float dn2 = dn * dn;
#pragma unroll
        for (int j = 0; j < 4; j++) acc[j] *= dn2;
    } else {
        acc = (float4v){0.f, 0.f, 0.f, 0.f};
    }

    int idxA[8]; float wtA[8];
#pragma unroll
    for (int u = 0; u < 8; u++) {                    // prologue: batch 0
        int ee = e0 + 2 * u + epar;
        int eec = (ee < N_EDGES) ? ee : (N_EDGES - 1);
        int s = esrc[eec];
        float wv = ewt[eec];
        idxA[u] = ((unsigned)s < N_NODES) ? s : 0;
        wtA[u] = (ee < e1) ? wv : 0.f;
    }

    for (int eb = e0; eb < e1; eb += 16) {
        float4v v[8];
#pragma unroll
        for (int u = 0; u < 8; u++) v[u] = x4[idxA[u] * 32 + l32];   // 16 gathers live
        int nb = eb + 16;
        int pb = (nb < e1) ? nb : eb;                // safe re-read on last batch
        int idxB[8]; float wtB[8];
#pragma unroll
        for (int u = 0; u < 8; u++) {                // prefetch next batch
            int ee = pb + 2 * u + epar;
            int eec = (ee < N_EDGES) ? ee : (N_EDGES - 1);
            int s = esrc[eec];
            float wv = ewt[eec];
            idxB[u] = ((unsigned)s < N_NODES) ? s : 0;
            wtB[u] = (ee < e1) ? wv : 0.f;
        }
#pragma unroll
        for (int u = 0; u < 8; u++) {
            float ww = dn * wtA[u];
#pragma unroll
            for (int j = 0; j < 4; j++) acc[j] += ww * v[u][j];
        }
#pragma unroll
        for (int u = 0; u < 8; u++) { idxA[u] = idxB[u]; wtA[u] = wtB[u]; }
    }

    float4v tot;
#pragma unroll
    for (int j = 0; j < 4; j++) tot[j] = acc[j] + __shfl_xor(acc[j], 32, 64);
    if (epar == 0)
        *(float4v*)(outf + node * 128 + l32 * 4) = tot;
}

// Final aggregate, BOTH branches in one wave: bufi is [node][branch][128], so
// lanes 0-31 (attr) + lanes 32-63 (struct) gather ONE contiguous 1KB block per
// edge. Half the latency chains of the y=2-grid version at identical traffic.
// Epilogue: attr half -> out_x fp32 (+b2a); struct half -> hs bf16 (+b2s).
__global__ void k_agg_fin(const float* __restrict__ bufi, const float* __restrict__ dinv,
                          const int* __restrict__ rptr, const int* __restrict__ esrc,
                          const float* __restrict__ ewt,
                          const float* __restrict__ ba, const float* __restrict__ bs,
                          float* __restrict__ out_x, bf16* __restrict__ hs) {
    int node = blockIdx.x * 4 + (threadIdx.x >> 6);
    int lane = threadIdx.x & 63;
    int half = lane >> 5;   // 0 = attr, 1 = struct
    int l32 = lane & 31;    // float4 column within the branch row
    const float4v* __restrict__ b4 = (const float4v*)bufi;  // (node,br) row = 32 float4
    float dn = dinv[node];
    int e0 = rptr[node], e1 = rptr[node + 1];

    float4v acc = b4[(node * 2 + half) * 32 + l32];
    float dn2 = dn * dn;
#pragma unroll
    for (int j = 0; j < 4; j++) acc[j] *= dn2;

    int idxA[8]; float wtA[8];
#pragma unroll
    for (int u = 0; u < 8; u++) {                    // prologue: batch 0 (wave-uniform)
        int ee = e0 + u;
        int eec = (ee < N_EDGES) ? ee : (N_EDGES - 1);
        int s = esrc[eec];
        float wv = ewt[eec];
        idxA[u] = ((unsigned)s < N_NODES) ? s : 0;
        wtA[u] = (ee < e1) ? wv : 0.f;
    }

    for (int eb = e0; eb < e1; eb += 8) {
        float4v v[8];
#pragma unroll
        for (int u = 0; u < 8; u++) v[u] = b4[(idxA[u] * 2 + half) * 32 + l32];
        int nb = eb + 8;
        int pb = (nb < e1) ? nb : eb;
        int idxB[8]; float wtB[8];
#pragma unroll
        for (int u = 0; u < 8; u++) {                // prefetch next batch
            int ee = pb + u;
            int eec = (ee < N_EDGES) ? ee : (N_EDGES - 1);
            int s = esrc[eec];
            float wv = ewt[eec];
            idxB[u] = ((unsigned)s < N_NODES) ? s : 0;
            wtB[u] = (ee < e1) ? wv : 0.f;
        }
#pragma unroll
        for (int u = 0; u < 8; u++) {
            float ww = dn * wtA[u];
#pragma unroll
            for (int j = 0; j < 4; j++) acc[j] += ww * v[u][j];
        }
#pragma unroll
        for (int u = 0; u < 8; u++) { idxA[u] = idxB[u]; wtA[u] = wtB[u]; }
    }

    const float* __restrict__ bias = half ? bs : ba;
    float4v bv = *(const float4v*)(bias + l32 * 4);
#pragma unroll
    for (int j = 0; j < 4; j++) acc[j] += bv[j];

    if (half == 0) {
        *(float4v*)(out_x + node * 128 + l32 * 4) = acc;
    } else {
        ushort4v p;
#pragma unroll
        for (int j = 0; j < 4; j++) {
            bf16 t = __float2bfloat16(acc[j]);
            p[j] = *reinterpret_cast<unsigned short*>(&t);
        }
        *(ushort4v*)((unsigned short*)hs + node * 128 + l32 * 4) = p;
    }
}

// Fused 2-layer MLP per block of 8 nodes, both branches via blockIdx.y:
//   phase1: h1[8][256] = relu(aggx[8 nodes][128] @ W1 + b1)  -> LDS (8 KB)
//   phase2: xw2[8][128] = h1 @ W2  -> bufi[node][br][128] (interleaved)
// LDS reads in phase2 are wave-uniform broadcasts -> conflict-free.
__global__ __launch_bounds__(256) void k_mlp(const float* __restrict__ aggx,
                                             const float* __restrict__ W1a,
                                             const float* __restrict__ W1s,
                                             const float* __restrict__ b1a,
                                             const float* __restrict__ b1s,
                                             const float* __restrict__ W2a,
                                             const float* __restrict__ W2s,
                                             float* __restrict__ bufi) {
    int br = blockIdx.y;
    const float* __restrict__ W1 = br ? W1s : W1a;
    const float* __restrict__ b1 = br ? b1s : b1a;
    const float* __restrict__ W2 = br ? W2s : W2a;

    __shared__ float h1[8][HID_DIM];  // 8 KB
    int t = threadIdx.x;
    int n0 = blockIdx.x * 8;

    // phase 1: t = hidden feature
    {
        float acc[8];
#pragma unroll
        for (int i = 0; i < 8; i++) acc[i] = 0.f;
        const float* __restrict__ Wf = W1 + t;
        const float* __restrict__ x0 = aggx + (size_t)n0 * IN_DIM;
        for (int k = 0; k < IN_DIM; k += 4) {
            float4v xr[8];
#pragma unroll
            for (int i = 0; i < 8; i++)
                xr[i] = *(const float4v*)(x0 + (size_t)i * IN_DIM + k);
#pragma unroll
            for (int kk = 0; kk < 4; kk++) {
                float w = Wf[(size_t)(k + kk) * HID_DIM];
#pragma unroll
                for (int i = 0; i < 8; i++) acc[i] += w * xr[i][kk];
            }
        }
        float b = b1[t];
#pragma unroll
        for (int i = 0; i < 8; i++) h1[i][t] = fmaxf(acc[i] + b, 0.f);
    }
    __syncthreads();

    // phase 2: f = t&127 output feature, half = t>>7 selects nodes 0-3 / 4-7
    {
        int f = t & 127;
        int half = t >> 7;
        float acc[4];
#pragma unroll
        for (int i = 0; i < 4; i++) acc[i] = 0.f;
        const float* __restrict__ Wf = W2 + f;
#pragma unroll 4
        for (int k = 0; k < HID_DIM; k++) {
            float w = Wf[(size_t)k * OUT_DIM];
#pragma unroll
            for (int i = 0; i < 4; i++) acc[i] += w * h1[half * 4 + i][k];
        }
#pragma unroll
        for (int i = 0; i < 4; i++) {
            int n = n0 + half * 4 + i;
            bufi[((size_t)n * 2 + br) * OUT_DIM + f] = acc[i];
        }
    }
}

// S = H * H^T, H: [N_NODES,128] bf16, S: [N_NODES,N_NODES] fp32.
// wave computes a 64x64 block (4x4 tiles of 16x16x32 MFMA); block = 4 waves -> 128x128.
// S is symmetric: store acc[ti][tj] TRANSPOSED so the MFMA reg axis becomes 4
// consecutive COLUMNS of S -> 16 dwordx4 stores/wave covering full 64B lines.
// Nontemporal: the 400 MB S-stream bypasses L2; hs panel stays resident.
__global__ __launch_bounds__(256) void k_sgemm(const bf16* __restrict__ H,
                                               float* __restrict__ S) {
    int w = threadIdx.x >> 6;
    int lane = threadIdx.x & 63;
    int i0 = blockIdx.y * 128 + (w & 1) * 64;
    int j0 = blockIdx.x * 128 + (w >> 1) * 64;
    int l15 = lane & 15;
    int quad = lane >> 4;

    float4v acc[4][4];
    for (int a = 0; a < 4; a++)
        for (int b = 0; b < 4; b++)
            acc[a][b] = (float4v){0.f, 0.f, 0.f, 0.f};

    const short* Hs = (const short*)H;
    for (int kk = 0; kk < 4; kk++) {
        int ko = kk * 32 + quad * 8;
        bshort8 af[4], bfr[4];
#pragma unroll
        for (int t = 0; t < 4; t++) {
            int r = i0 + t * 16 + l15;
            if (r >= N_NODES) r = 0;
            af[t] = *(const bshort8*)(Hs + r * IN_DIM + ko);
            int c = j0 + t * 16 + l15;
            if (c >= N_NODES) c = 0;
            bfr[t] = *(const bshort8*)(Hs + c * IN_DIM + ko);
        }
#pragma unroll
        for (int ti = 0; ti < 4; ti++)
#pragma unroll
            for (int tj = 0; tj < 4; tj++)
                acc[ti][tj] = __builtin_amdgcn_mfma_f32_16x16x32_bf16(
                    af[ti], bfr[tj], acc[ti][tj], 0, 0, 0);
    }

    // transposed (symmetric) store: D[m][n] = S[i0+m][j0+n] = S[j0+n][i0+m]
#pragma unroll
    for (int ti = 0; ti < 4; ti++) {
        int cbase = i0 + ti * 16 + quad * 4;     // 4 consecutive cols (cbase % 4 == 0)
        if (cbase >= N_NODES) continue;          // N % 4 == 0 -> all-or-nothing
#pragma unroll
        for (int tj = 0; tj < 4; tj++) {
            int row = j0 + tj * 16 + l15;
            if (row >= N_NODES) continue;
            __builtin_nontemporal_store(acc[ti][tj],
                                        (float4v*)(S + (size_t)row * N_NODES + cbase));
        }
    }
}

extern "C" void kernel_launch(void* const* d_in, const int* in_sizes, int n_in,
                              void* d_out, int out_size, void* d_ws, size_t ws_size,
                              hipStream_t stream) {
    const float* h   = (const float*)d_in[0];
    const float* W1a = (const float*)d_in[1];
    const float* b1a = (const float*)d_in[2];
    const float* W2a = (const float*)d_in[3];
    const float* b2a = (const float*)d_in[4];
    const float* W1s = (const float*)d_in[5];
    const float* b1s = (const float*)d_in[6];
    const float* W2s = (const float*)d_in[7];
    const float* b2s = (const float*)d_in[8];
    const int* edge  = (const int*)d_in[9];
    const int* src = edge;
    const int* dst = edge + N_EDGES;

    char* ob = (char*)d_out;
    float* aggx = (float*)(ob + SC_AGGX);
    float* bufi = (float*)(ob + SC_BUFI);
    int*   esrc = (int*)(ob + SC_ESRC);
    float* ewt  = (float*)(ob + SC_EWT);
    int*   cnt  = (int*)(ob + SC_CNT);
    int*   cur  = (int*)(ob + SC_CUR);
    int*   rptr = (int*)(ob + SC_RPTR);
    float* dinv = (float*)(ob + SC_DINV);
    bf16*  hs   = (bf16*)(ob + OFF_HS);   // staged in out_h region

    float* out   = (float*)d_out;
    float* out_x = out;                                   // [10000,128]
    float* out_s = out + (size_t)N_NODES * OUT_DIM;       // [10000,10000]
    float* out_h = out_s + (size_t)N_NODES * N_NODES;     // [10000,128]

    // graph prep: degree histogram -> scan -> CSR fill (+ per-edge weight)
    k_zero<<<(N_NODES + 255) / 256, 256, 0, stream>>>(cnt, cur);
    k_hist<<<(N_EDGES + 255) / 256, 256, 0, stream>>>(dst, cnt);
    k_scan<<<1, 1024, 0, stream>>>(cnt, rptr, dinv);
    k_fill<<<(N_EDGES + 255) / 256, 256, 0, stream>>>(src, dst, rptr, cur,
                                                      dinv, esrc, ewt);

    // shared layer-1 aggregation: aggx = A_norm * x (GCN conv is linear:
    // A(xW)+b == (Ax)W+b, and Ax is branch-independent)
    k_agg_one<<<N_NODES / 4, 256, 0, stream>>>(h, dinv, rptr, esrc, ewt, aggx);

    // fused MLP: relu(aggx@W1+b1)@W2 for both branches -> interleaved bufi
    k_mlp<<<dim3(N_NODES / 8, 2), 256, 0, stream>>>(
        aggx, W1a, W1s, b1a, b1s, W2a, W2s, bufi);

    // layer 2 aggregate (both branches per wave) -> out_x (fp32) / hs (bf16)
    k_agg_fin<<<N_NODES / 4, 256, 0, stream>>>(
        bufi, dinv, rptr, esrc, ewt, b2a, b2s, out_x, hs);

    // s_ = h_ @ h_^T  (reads bf16 hs from out_h region, writes fp32 out_s)
    dim3 g((N_NODES + 127) / 128, (N_NODES + 127) / 128);
    k_sgemm<<<g, 256, 0, stream>>>(hs, out_s);

    // third output: h passthrough (overwrites hs staging in out_h)
    hipMemcpyAsync(out_h, h, (size_t)N_NODES * IN_DIM * sizeof(float),
                   hipMemcpyDeviceToDevice, stream);
}